// Round 1
// baseline (1124.539 us; speedup 1.0000x reference)
//
#include <hip/hip_runtime.h>

// Problem constants: V=50000 D=300 H=512 CO=100 B=64 S=32 W=128
// Sentences: B*S = 2048, tokens/sentence = 128.

#define LDSROWS 132   // 128 token rows + 4 zero halo rows (conv5 shift)
#define LDSK    328   // padded K stride (656B rows -> 2-way-max LDS bank aliasing, free)

typedef __bf16   bf16x8 __attribute__((ext_vector_type(8)));
typedef float    f32x4  __attribute__((ext_vector_type(4)));
typedef _Float16 h2v    __attribute__((ext_vector_type(2)));

// ---------------- P1: conv weights -> MFMA A-matrix bf16 [1344][320] ----------------
// Row regions: conv3 rows 0..335, conv4 336..783, conv5 784..1343.
// Within a conv of window kc: row = (cg*kc + j)*16 + t, channel = cg*16 + t (pad ch>=100 -> 0).
__global__ void prep_convw(const float* __restrict__ w3, const float* __restrict__ w4,
                           const float* __restrict__ w5, __bf16* __restrict__ Aw) {
  int idx = blockIdx.x * 256 + threadIdx.x;
  if (idx >= 1344 * 320) return;
  int row = idx / 320, k = idx - row * 320;
  int kc, rr; const float* w;
  if (row < 336)      { kc = 3; rr = row;       w = w3; }
  else if (row < 784) { kc = 4; rr = row - 336; w = w4; }
  else                { kc = 5; rr = row - 784; w = w5; }
  int cgj = rr >> 4, t = rr & 15;
  int cg = cgj / kc, j = cgj - cg * kc;
  int ch = cg * 16 + t;
  float v = 0.f;
  if (ch < 100 && k < 300) v = w[(ch * kc + j) * 300 + k];
  Aw[idx] = (__bf16)v;
}

// ---------------- P2: W_hh (f/b) -> f16 pairs, Wp[dir][kp][o] = (W[o][2kp], W[o][2kp+1]) ------
__global__ void prep_whh(const float* __restrict__ whf, const float* __restrict__ whb,
                         h2v* __restrict__ Wp) {
  int idx = blockIdx.x * 256 + threadIdx.x;
  if (idx >= 2 * 256 * 512) return;
  int dir = idx >> 17;
  int rem = idx & 131071;
  int kp = rem >> 9, o = rem & 511;
  const float* W = dir ? whb : whf;
  h2v h;
  h[0] = (_Float16)W[o * 512 + 2 * kp];
  h[1] = (_Float16)W[o * 512 + 2 * kp + 1];
  Wp[idx] = h;
}

// ---------------- conv chunk: NCG channel-groups of one conv, j-shift baked into B reads ------
template<int NCG>
__device__ __forceinline__ void conv_chunk(const __bf16* lds, const __bf16* __restrict__ Aw,
                                           int Rc, int kc, int cg0, const float* __restrict__ bias,
                                           int colbase, int pmax, float* __restrict__ srow, int lane) {
  const int lrow = lane & 15, lk = (lane >> 4) * 8;
  f32x4 acc[NCG][8];
#pragma unroll
  for (int i = 0; i < NCG; ++i)
#pragma unroll
    for (int n = 0; n < 8; ++n) acc[i][n] = (f32x4){0.f, 0.f, 0.f, 0.f};

  for (int j = 0; j < kc; ++j) {           // j-shift: B reads LDS row p+j
#pragma unroll
    for (int ks = 0; ks < 10; ++ks) {      // K = 320 = 10 * 32
      bf16x8 bf[8];
#pragma unroll
      for (int nt = 0; nt < 8; ++nt) {
        int row = nt * 16 + lrow + j;
        bf[nt] = *(const bf16x8*)(lds + row * LDSK + ks * 32 + lk);
      }
#pragma unroll
      for (int i = 0; i < NCG; ++i) {
        int arow = Rc + ((cg0 + i) * kc + j) * 16 + lrow;
        bf16x8 af = *(const bf16x8*)(Aw + (size_t)arow * 320 + ks * 32 + lk);
#pragma unroll
        for (int nt = 0; nt < 8; ++nt)
          acc[i][nt] = __builtin_amdgcn_mfma_f32_16x16x32_bf16(af, bf[nt], acc[i][nt], 0, 0, 0);
      }
    }
  }
  // epilogue: +bias, relu, mask invalid positions, max over p (8 tiles elementwise + 16-lane reduce)
#pragma unroll
  for (int i = 0; i < NCG; ++i) {
    int chbase = (cg0 + i) * 16 + ((lane >> 4) * 4);
    float bv[4];
#pragma unroll
    for (int r = 0; r < 4; ++r) bv[r] = ((chbase + r) < 100) ? bias[chbase + r] : 0.f;
    float m[4] = {0.f, 0.f, 0.f, 0.f};
#pragma unroll
    for (int nt = 0; nt < 8; ++nt) {
      int p = nt * 16 + lrow;
      bool valid = (p <= pmax);
#pragma unroll
      for (int r = 0; r < 4; ++r) {
        float v = acc[i][nt][r] + bv[r];
        v = fmaxf(v, 0.f);
        if (!valid) v = 0.f;
        m[r] = fmaxf(m[r], v);
      }
    }
#pragma unroll
    for (int r = 0; r < 4; ++r) {
#pragma unroll
      for (int d = 1; d < 16; d <<= 1) m[r] = fmaxf(m[r], __shfl_xor(m[r], d, 64));
      int ch = chbase + r;
      if (lrow == 0 && ch < 100) srow[colbase + ch] = m[r];
    }
  }
}

// ---------------- K1: per-sentence conv+relu+maxpool -> sent[2048][300] f32 -------------------
__global__ void __launch_bounds__(256, 1)
conv_kernel(const int* __restrict__ tok, const float* __restrict__ emb,
            const __bf16* __restrict__ Aw,
            const float* __restrict__ b3, const float* __restrict__ b4, const float* __restrict__ b5,
            float* __restrict__ sent) {
  extern __shared__ __bf16 lds[];          // [LDSROWS][LDSK] bf16 = 86592 B
  const int sid = blockIdx.x, tid = threadIdx.x;
  for (int i = tid; i < (LDSROWS * LDSK) / 2; i += 256) ((unsigned int*)lds)[i] = 0u;
  __syncthreads();
  const int* t0 = tok + sid * 128;
  for (int i = tid; i < 128 * 75; i += 256) {       // 75 float4 per 300-dim embedding row
    int r = i / 75, q = i - r * 75;
    long tk = (long)t0[r];
    float4 v = *(const float4*)(emb + tk * 300L + q * 4);
    __bf16* d = lds + r * LDSK + q * 4;
    d[0] = (__bf16)v.x; d[1] = (__bf16)v.y; d[2] = (__bf16)v.z; d[3] = (__bf16)v.w;
  }
  __syncthreads();
  const int wave = tid >> 6, lane = tid & 63;
  float* srow = sent + sid * 300;
  // static worklist: R3=0 R4=336 R5=784 ; pmax = 128-kc ; frag-work per wave = 21/21/20/22
  switch (wave) {
    case 0:
      conv_chunk<3>(lds, Aw, 784, 5, 0, b5, 200, 123, srow, lane);
      conv_chunk<2>(lds, Aw,   0, 3, 0, b3,   0, 125, srow, lane);
      break;
    case 1:
      conv_chunk<3>(lds, Aw, 784, 5, 3, b5, 200, 123, srow, lane);
      conv_chunk<2>(lds, Aw,   0, 3, 2, b3,   0, 125, srow, lane);
      break;
    case 2:
      conv_chunk<1>(lds, Aw, 784, 5, 6, b5, 200, 123, srow, lane);
      conv_chunk<3>(lds, Aw, 336, 4, 0, b4, 100, 124, srow, lane);
      conv_chunk<1>(lds, Aw,   0, 3, 4, b3,   0, 125, srow, lane);
      break;
    default:
      conv_chunk<3>(lds, Aw, 336, 4, 3, b4, 100, 124, srow, lane);
      conv_chunk<1>(lds, Aw, 336, 4, 6, b4, 100, 124, srow, lane);
      conv_chunk<2>(lds, Aw,   0, 3, 5, b3,   0, 125, srow, lane);
      break;
  }
}

// ---------------- K2: XI = sent @ proj_w^T + proj_b  (8 rows/block) ---------------------------
__global__ void xi_kernel(const float* __restrict__ sent, const float* __restrict__ pw,
                          const float* __restrict__ pb, float* __restrict__ XI) {
  __shared__ float s[8][300];
  const int rb = blockIdx.x * 8, tid = threadIdx.x;
  for (int i = tid; i < 8 * 300; i += 256) { int r = i / 300, c = i - r * 300; s[r][c] = sent[(rb + r) * 300 + c]; }
  __syncthreads();
  for (int o = tid; o < 300; o += 256) {
    const float* w = pw + o * 300;
    float bvv = pb[o];
    float a[8];
#pragma unroll
    for (int r = 0; r < 8; ++r) a[r] = bvv;
    for (int k = 0; k < 300; k += 4) {
      float4 wv = *(const float4*)(w + k);
#pragma unroll
      for (int r = 0; r < 8; ++r)
        a[r] += wv.x * s[r][k] + wv.y * s[r][k + 1] + wv.z * s[r][k + 2] + wv.w * s[r][k + 3];
    }
#pragma unroll
    for (int r = 0; r < 8; ++r) XI[(rb + r) * 300 + o] = a[r];
  }
}

// ---------------- K3: G = XI @ [w_ih_f;w_ih_b]^T + (b_ih+b_hh)  [2048][1024] ------------------
__global__ void g_kernel(const float* __restrict__ XI,
                         const float* __restrict__ wf, const float* __restrict__ wb,
                         const float* __restrict__ bif, const float* __restrict__ bhf,
                         const float* __restrict__ bib, const float* __restrict__ bhb,
                         float* __restrict__ G) {
  __shared__ float s[8][300];
  const int rb = blockIdx.x * 8, tid = threadIdx.x;
  for (int i = tid; i < 8 * 300; i += 256) { int r = i / 300, c = i - r * 300; s[r][c] = XI[(rb + r) * 300 + c]; }
  __syncthreads();
  for (int o = tid; o < 1024; o += 256) {
    int dir = o >> 9, oo = o & 511;
    const float* w = (dir ? wb : wf) + oo * 300;
    float bvv = dir ? (bib[oo] + bhb[oo]) : (bif[oo] + bhf[oo]);
    float a[8];
#pragma unroll
    for (int r = 0; r < 8; ++r) a[r] = bvv;
    for (int k = 0; k < 300; k += 4) {
      float4 wv = *(const float4*)(w + k);
#pragma unroll
      for (int r = 0; r < 8; ++r)
        a[r] += wv.x * s[r][k] + wv.y * s[r][k + 1] + wv.z * s[r][k + 2] + wv.w * s[r][k + 3];
    }
#pragma unroll
    for (int r = 0; r < 8; ++r) G[(rb + r) * 1024 + o] = a[r];
  }
}

// ---------------- K3b: h0 = sent[:,0,:] @ init_w^T + init_b  [64][512] ------------------------
__global__ void h0_kernel(const float* __restrict__ sent, const float* __restrict__ iw,
                          const float* __restrict__ ib, float* __restrict__ h0) {
  __shared__ float s[8][300];
  const int bb = blockIdx.x * 8, tid = threadIdx.x;
  for (int i = tid; i < 8 * 300; i += 256) { int r = i / 300, c = i - r * 300; s[r][c] = sent[((bb + r) * 32) * 300 + c]; }
  __syncthreads();
  for (int o = tid; o < 512; o += 256) {
    const float* w = iw + o * 300;
    float bvv = ib[o];
    float a[8];
#pragma unroll
    for (int r = 0; r < 8; ++r) a[r] = bvv;
    for (int k = 0; k < 300; k += 4) {
      float4 wv = *(const float4*)(w + k);
#pragma unroll
      for (int r = 0; r < 8; ++r)
        a[r] += wv.x * s[r][k] + wv.y * s[r][k + 1] + wv.z * s[r][k + 2] + wv.w * s[r][k + 3];
    }
#pragma unroll
    for (int r = 0; r < 8; ++r) h0[(bb + r) * 512 + o] = a[r];
  }
}

// ---------------- K4: persistent RNN, one block per (dir, batch) chain ------------------------
#if __has_builtin(__builtin_amdgcn_fdot2)
#define FDOT2(a, b, c) __builtin_amdgcn_fdot2((a), (b), (c), false)
#else
static __device__ __forceinline__ float FDOT2(h2v a, h2v b, float c) {
  return c + (float)a[0] * (float)b[0] + (float)a[1] * (float)b[1];
}
#endif

__global__ void __launch_bounds__(256)
rnn_kernel(const h2v* __restrict__ Wp, const float* __restrict__ G,
           const float* __restrict__ h0, float* __restrict__ H) {
  const int blk = blockIdx.x, tid = threadIdx.x;
  const int dir = blk >> 6, b = blk & 63;
  __shared__ float hs[512];
  __shared__ h2v  h2s[256];
  for (int i = tid; i < 512; i += 256) hs[i] = h0[b * 512 + i];
  __syncthreads();
  const h2v* W = Wp + (size_t)dir * (256 * 512);
  for (int t = 0; t < 32; ++t) {
    { h2v hh; hh[0] = (_Float16)hs[2 * tid]; hh[1] = (_Float16)hs[2 * tid + 1]; h2s[tid] = hh; }
    __syncthreads();
    const float* g = G + ((size_t)(b * 32 + t)) * 1024 + dir * 512;
    float a0 = g[tid], a1 = g[tid + 256];
#pragma unroll 8
    for (int kp = 0; kp < 256; ++kp) {
      h2v h2 = h2s[kp];
      a0 = FDOT2(W[kp * 512 + tid], h2, a0);
      a1 = FDOT2(W[kp * 512 + tid + 256], h2, a1);
    }
    __syncthreads();
    float n0 = tanhf(a0), n1 = tanhf(a1);
    hs[tid] = n0; hs[tid + 256] = n1;
    float* Ht = H + ((size_t)((dir * 64 + b) * 32 + t)) * 512;
    Ht[tid] = n0; Ht[tid + 256] = n1;
    __syncthreads();
  }
}

// ---------------- K5: preds = [hf;hb] @ cls_w^T + cls_b -> out[64][32][5] ---------------------
__global__ void pred_kernel(const float* __restrict__ H, const float* __restrict__ cw,
                            const float* __restrict__ cb, float* __restrict__ out) {
  const int bt = blockIdx.x;            // b*32 + t
  const int lane = threadIdx.x;         // 64
  const int b = bt >> 5, t = bt & 31;
  const float* hf = H + ((size_t)(b * 32 + t)) * 512;
  const float* hb = H + ((size_t)((64 + b) * 32 + t)) * 512;
  for (int c = 0; c < 5; ++c) {
    const float* w = cw + c * 1024;
    float a = 0.f;
    for (int o = lane; o < 512; o += 64) a += w[o] * hf[o] + w[512 + o] * hb[o];
#pragma unroll
    for (int d = 32; d; d >>= 1) a += __shfl_down(a, d, 64);
    if (lane == 0) out[bt * 5 + c] = a + cb[c];
  }
}

// ------------------------------------------------------------------------------------------------
extern "C" void kernel_launch(void* const* d_in, const int* in_sizes, int n_in,
                              void* d_out, int out_size, void* d_ws, size_t ws_size,
                              hipStream_t stream) {
  const int*   tok  = (const int*)d_in[0];
  const float* emb  = (const float*)d_in[1];
  const float* w3   = (const float*)d_in[2];
  const float* b3   = (const float*)d_in[3];
  const float* w4   = (const float*)d_in[4];
  const float* b4   = (const float*)d_in[5];
  const float* w5   = (const float*)d_in[6];
  const float* b5   = (const float*)d_in[7];
  const float* pw   = (const float*)d_in[8];
  const float* pb   = (const float*)d_in[9];
  const float* iw   = (const float*)d_in[10];
  const float* ib   = (const float*)d_in[11];
  const float* wihf = (const float*)d_in[12];
  const float* whhf = (const float*)d_in[13];
  const float* bihf = (const float*)d_in[14];
  const float* bhhf = (const float*)d_in[15];
  const float* wihb = (const float*)d_in[16];
  const float* whhb = (const float*)d_in[17];
  const float* bihb = (const float*)d_in[18];
  const float* bhhb = (const float*)d_in[19];
  const float* cw   = (const float*)d_in[20];
  const float* cb   = (const float*)d_in[21];
  float* out = (float*)d_out;

  char* ws = (char*)d_ws;
  __bf16* Aw   = (__bf16*)(ws);                         //  0MB: 860 KB
  h2v*   Wp    = (h2v*)  (ws +  1u * 1024 * 1024);      //  1MB: 1 MB
  float* sent  = (float*)(ws +  2u * 1024 * 1024);      //  2MB: 2.4 MB
  float* XI    = (float*)(ws +  5u * 1024 * 1024);      //  5MB: 2.4 MB
  float* G     = (float*)(ws +  8u * 1024 * 1024);      //  8MB: 8 MB
  float* h0    = (float*)(ws + 16u * 1024 * 1024);      // 16MB: 128 KB
  float* H     = (float*)(ws + 17u * 1024 * 1024);      // 17MB: 16 MB (end 33MB)

  prep_convw<<<1680, 256, 0, stream>>>(w3, w4, w5, Aw);
  prep_whh<<<1024, 256, 0, stream>>>(whhf, whhb, Wp);

  const int ldsbytes = LDSROWS * LDSK * 2;              // 86592 B (> 64KB -> opt-in)
  hipFuncSetAttribute(reinterpret_cast<const void*>(conv_kernel),
                      hipFuncAttributeMaxDynamicSharedMemorySize, ldsbytes);
  conv_kernel<<<2048, 256, ldsbytes, stream>>>(tok, emb, Aw, b3, b4, b5, sent);

  xi_kernel<<<256, 256, 0, stream>>>(sent, pw, pb, XI);
  g_kernel<<<256, 256, 0, stream>>>(XI, wihf, wihb, bihf, bhhf, bihb, bhhb, G);
  h0_kernel<<<8, 256, 0, stream>>>(sent, iw, ib, h0);
  rnn_kernel<<<128, 256, 0, stream>>>(Wp, G, h0, H);
  pred_kernel<<<2048, 64, 0, stream>>>(H, cw, cb, out);
}

// Round 3
// 761.982 us; speedup vs baseline: 1.4758x; 1.4758x over previous
//
#include <hip/hip_runtime.h>

// Problem constants: V=50000 D=300 H=512 CO=100 B=64 S=32 W=128
// Sentences: B*S = 2048, tokens/sentence = 128.
//
// Conv LDS tile: rows 0..131 (128 tokens + 4 zero halo), K-stride 304 bf16, LINEAR
// (no swizzle -- round-2's +8 additive swizzle overlapped row r tail into row r+1
// head and corrupted embeddings; and bank analysis shows ds_read_b128 group
// occupancy is already even at stride 304: group=(6*row+chunk)%8, 8 lanes/group).
// Reads at k>=300 hit zero slack (elems 300..303) or next-row data (304..319);
// the A matrix is zero-padded for k>=300 so those products contribute 0.
// 80288 B/block -> 2 blocks/CU -> 8 waves/CU.

#define LDSK     304
#define LDSELEMS 40144            // 131*304 + 320 covers row-131 tail reads (max 40143)
#define LDSBYTES 80288

typedef __bf16   bf16x8 __attribute__((ext_vector_type(8)));
typedef float    f32x4  __attribute__((ext_vector_type(4)));
typedef _Float16 h2v    __attribute__((ext_vector_type(2)));

// ---------------- P1: conv weights -> MFMA A-matrix bf16 [1344][320] ----------------
// conv3 rows 0..335, conv4 336..783, conv5 784..1343.
// row = (cg*kc + j)*16 + t, channel = cg*16 + t (ch>=100 and k>=300 zero-padded).
__global__ void prep_convw(const float* __restrict__ w3, const float* __restrict__ w4,
                           const float* __restrict__ w5, __bf16* __restrict__ Aw) {
  int idx = blockIdx.x * 256 + threadIdx.x;
  if (idx >= 1344 * 320) return;
  int row = idx / 320, k = idx - row * 320;
  int kc, rr; const float* w;
  if (row < 336)      { kc = 3; rr = row;       w = w3; }
  else if (row < 784) { kc = 4; rr = row - 336; w = w4; }
  else                { kc = 5; rr = row - 784; w = w5; }
  int cgj = rr >> 4, t = rr & 15;
  int cg = cgj / kc, j = cgj - cg * kc;
  int ch = cg * 16 + t;
  float v = 0.f;
  if (ch < 100 && k < 300) v = w[(ch * kc + j) * 300 + k];
  Aw[idx] = (__bf16)v;
}

// ---------------- P2: W_hh -> 16B-load layout -------------------------------------------------
// Wq[dir][kq][tid] (uint4): x=pack(W[tid][4kq],W[tid][4kq+1]) y=pack(W[tid+256][4kq],..+1)
//                           z=pack(W[tid][4kq+2],..+3)        w=pack(W[tid+256][4kq+2],..+3)
__device__ __forceinline__ unsigned int packf16(float a, float b) {
  h2v h; h[0] = (_Float16)a; h[1] = (_Float16)b;
  return __builtin_bit_cast(unsigned int, h);
}
__global__ void prep_whh(const float* __restrict__ whf, const float* __restrict__ whb,
                         uint4* __restrict__ Wq) {
  int idx = blockIdx.x * 256 + threadIdx.x;
  if (idx >= 2 * 128 * 256) return;
  int dir = idx >> 15;
  int rem = idx & 32767;
  int kq = rem >> 8, tid = rem & 255;
  const float* W = dir ? whb : whf;
  const float* r0 = W + (size_t)tid * 512 + 4 * kq;
  const float* r1 = W + (size_t)(tid + 256) * 512 + 4 * kq;
  uint4 o;
  o.x = packf16(r0[0], r0[1]);
  o.y = packf16(r1[0], r1[1]);
  o.z = packf16(r0[2], r0[3]);
  o.w = packf16(r1[2], r1[3]);
  Wq[idx] = o;
}

// ---------------- conv chunk: NCG channel-groups of one conv, j-shift baked into B reads ------
template<int NCG>
__device__ __forceinline__ void conv_chunk(const __bf16* lds, const __bf16* __restrict__ Aw,
                                           int Rc, int kc, int cg0, const float* __restrict__ bias,
                                           int colbase, int pmax, float* __restrict__ srow, int lane) {
  const int lrow = lane & 15, lk = (lane >> 4) * 8;
  f32x4 acc[NCG][8];
#pragma unroll
  for (int i = 0; i < NCG; ++i)
#pragma unroll
    for (int n = 0; n < 8; ++n) acc[i][n] = (f32x4){0.f, 0.f, 0.f, 0.f};

  for (int j = 0; j < kc; ++j) {           // j-shift: B reads LDS row p+j
    const __bf16* bbase = lds + (lrow + j) * LDSK + lk;
#pragma unroll
    for (int ks = 0; ks < 10; ++ks) {      // K = 320 = 10 * 32
      bf16x8 bf[8];
#pragma unroll
      for (int nt = 0; nt < 8; ++nt)
        bf[nt] = *(const bf16x8*)(bbase + nt * (16 * LDSK) + ks * 32);
#pragma unroll
      for (int i = 0; i < NCG; ++i) {
        int arow = Rc + ((cg0 + i) * kc + j) * 16 + lrow;
        bf16x8 af = *(const bf16x8*)(Aw + (size_t)arow * 320 + ks * 32 + lk);
#pragma unroll
        for (int nt = 0; nt < 8; ++nt)
          acc[i][nt] = __builtin_amdgcn_mfma_f32_16x16x32_bf16(af, bf[nt], acc[i][nt], 0, 0, 0);
      }
    }
  }
  // epilogue: +bias, relu, mask invalid positions, max over p
#pragma unroll
  for (int i = 0; i < NCG; ++i) {
    int chbase = (cg0 + i) * 16 + ((lane >> 4) * 4);
    float bv[4];
#pragma unroll
    for (int r = 0; r < 4; ++r) bv[r] = ((chbase + r) < 100) ? bias[chbase + r] : 0.f;
    float m[4] = {0.f, 0.f, 0.f, 0.f};
#pragma unroll
    for (int nt = 0; nt < 8; ++nt) {
      int p = nt * 16 + lrow;
      bool valid = (p <= pmax);
#pragma unroll
      for (int r = 0; r < 4; ++r) {
        float v = acc[i][nt][r] + bv[r];
        v = fmaxf(v, 0.f);
        if (!valid) v = 0.f;
        m[r] = fmaxf(m[r], v);
      }
    }
#pragma unroll
    for (int r = 0; r < 4; ++r) {
#pragma unroll
      for (int d = 1; d < 16; d <<= 1) m[r] = fmaxf(m[r], __shfl_xor(m[r], d, 64));
      int ch = chbase + r;
      if (lrow == 0 && ch < 100) srow[colbase + ch] = m[r];
    }
  }
}

// ---------------- K1: per-sentence conv+relu+maxpool -> sent[2048][300] f32 -------------------
__global__ void __launch_bounds__(256, 2)
conv_kernel(const int* __restrict__ tok, const float* __restrict__ emb,
            const __bf16* __restrict__ Aw,
            const float* __restrict__ b3, const float* __restrict__ b4, const float* __restrict__ b5,
            float* __restrict__ sent) {
  extern __shared__ __bf16 lds[];          // LDSBYTES (80288)
  const int sid = blockIdx.x, tid = threadIdx.x;
  for (int i = tid; i < LDSBYTES / 4; i += 256) ((unsigned int*)lds)[i] = 0u;
  __syncthreads();
  const int* t0 = tok + sid * 128;
  for (int i = tid; i < 128 * 75; i += 256) {       // 75 float4 per 300-dim embedding row
    int r = i / 75, q = i - r * 75;
    long tk = (long)t0[r];
    float4 v = *(const float4*)(emb + tk * 300L + q * 4);
    union { __bf16 h[4]; uint2 u; } pk;
    pk.h[0] = (__bf16)v.x; pk.h[1] = (__bf16)v.y; pk.h[2] = (__bf16)v.z; pk.h[3] = (__bf16)v.w;
    *(uint2*)(lds + r * LDSK + q * 4) = pk.u;       // 8B aligned, rows 0..299 only
  }
  __syncthreads();
  const int wave = tid >> 6, lane = tid & 63;
  float* srow = sent + sid * 300;
  // static worklist: R3=0 R4=336 R5=784 ; pmax = 128-kc
  switch (wave) {
    case 0:
      conv_chunk<3>(lds, Aw, 784, 5, 0, b5, 200, 123, srow, lane);
      conv_chunk<2>(lds, Aw,   0, 3, 0, b3,   0, 125, srow, lane);
      break;
    case 1:
      conv_chunk<3>(lds, Aw, 784, 5, 3, b5, 200, 123, srow, lane);
      conv_chunk<2>(lds, Aw,   0, 3, 2, b3,   0, 125, srow, lane);
      break;
    case 2:
      conv_chunk<1>(lds, Aw, 784, 5, 6, b5, 200, 123, srow, lane);
      conv_chunk<3>(lds, Aw, 336, 4, 0, b4, 100, 124, srow, lane);
      conv_chunk<1>(lds, Aw,   0, 3, 4, b3,   0, 125, srow, lane);
      break;
    default:
      conv_chunk<3>(lds, Aw, 336, 4, 3, b4, 100, 124, srow, lane);
      conv_chunk<1>(lds, Aw, 336, 4, 6, b4, 100, 124, srow, lane);
      conv_chunk<2>(lds, Aw,   0, 3, 5, b3,   0, 125, srow, lane);
      break;
  }
}

// ---------------- K2: fused XI = sent@proj^T+pb ; G = XI@[w_ih_f;w_ih_b]^T + biases -----------
__global__ void xig_kernel(const float* __restrict__ sent,
                           const float* __restrict__ pw, const float* __restrict__ pb,
                           const float* __restrict__ wf, const float* __restrict__ wb,
                           const float* __restrict__ bif, const float* __restrict__ bhf,
                           const float* __restrict__ bib, const float* __restrict__ bhb,
                           float* __restrict__ G) {
  __shared__ float s[8][300];
  __shared__ float xi[8][304];
  const int rb = blockIdx.x * 8, tid = threadIdx.x;
  for (int i = tid; i < 8 * 300; i += 256) { int r = i / 300, c = i - r * 300; s[r][c] = sent[(rb + r) * 300 + c]; }
  __syncthreads();
  for (int o = tid; o < 300; o += 256) {
    const float* w = pw + o * 300;
    float bvv = pb[o];
    float a[8];
#pragma unroll
    for (int r = 0; r < 8; ++r) a[r] = bvv;
    for (int k = 0; k < 300; k += 4) {
      float4 wv = *(const float4*)(w + k);
#pragma unroll
      for (int r = 0; r < 8; ++r)
        a[r] += wv.x * s[r][k] + wv.y * s[r][k + 1] + wv.z * s[r][k + 2] + wv.w * s[r][k + 3];
    }
#pragma unroll
    for (int r = 0; r < 8; ++r) xi[r][o] = a[r];
  }
  __syncthreads();
  for (int o = tid; o < 1024; o += 256) {
    int dir = o >> 9, oo = o & 511;
    const float* w = (dir ? wb : wf) + oo * 300;
    float bvv = dir ? (bib[oo] + bhb[oo]) : (bif[oo] + bhf[oo]);
    float a[8];
#pragma unroll
    for (int r = 0; r < 8; ++r) a[r] = bvv;
    for (int k = 0; k < 300; k += 4) {
      float4 wv = *(const float4*)(w + k);
#pragma unroll
      for (int r = 0; r < 8; ++r)
        a[r] += wv.x * xi[r][k] + wv.y * xi[r][k + 1] + wv.z * xi[r][k + 2] + wv.w * xi[r][k + 3];
    }
#pragma unroll
    for (int r = 0; r < 8; ++r) G[(rb + r) * 1024 + o] = a[r];
  }
}

// ---------------- K3: h0 = sent[:,0,:] @ init_w^T + init_b  [64][512] ------------------------
__global__ void h0_kernel(const float* __restrict__ sent, const float* __restrict__ iw,
                          const float* __restrict__ ib, float* __restrict__ h0) {
  __shared__ float s[8][300];
  const int bb = blockIdx.x * 8, tid = threadIdx.x;
  for (int i = tid; i < 8 * 300; i += 256) { int r = i / 300, c = i - r * 300; s[r][c] = sent[((bb + r) * 32) * 300 + c]; }
  __syncthreads();
  for (int o = tid; o < 512; o += 256) {
    const float* w = iw + o * 300;
    float bvv = ib[o];
    float a[8];
#pragma unroll
    for (int r = 0; r < 8; ++r) a[r] = bvv;
    for (int k = 0; k < 300; k += 4) {
      float4 wv = *(const float4*)(w + k);
#pragma unroll
      for (int r = 0; r < 8; ++r)
        a[r] += wv.x * s[r][k] + wv.y * s[r][k + 1] + wv.z * s[r][k + 2] + wv.w * s[r][k + 3];
    }
#pragma unroll
    for (int r = 0; r < 8; ++r) h0[(bb + r) * 512 + o] = a[r];
  }
}

// ---------------- K4: persistent RNN, one block per (dir, batch) chain ------------------------
#if __has_builtin(__builtin_amdgcn_fdot2)
#define FDOT2(a, b, c) __builtin_amdgcn_fdot2((a), (b), (c), false)
#else
static __device__ __forceinline__ float FDOT2(h2v a, h2v b, float c) {
  return c + (float)a[0] * (float)b[0] + (float)a[1] * (float)b[1];
}
#endif
__device__ __forceinline__ h2v as_h2(unsigned int u) { return __builtin_bit_cast(h2v, u); }

__global__ void __launch_bounds__(256)
rnn_kernel(const uint4* __restrict__ Wq, const float* __restrict__ G,
           const float* __restrict__ h0, float* __restrict__ H) {
  const int blk = blockIdx.x, tid = threadIdx.x;
  const int dir = blk >> 6, b = blk & 63;
  __shared__ float hs[512];
  __shared__ uint2 h2p[128];
  for (int i = tid; i < 512; i += 256) hs[i] = h0[b * 512 + i];
  __syncthreads();
  const uint4* W = Wq + (size_t)dir * (128 * 256);
  for (int t = 0; t < 32; ++t) {
    { h2v hh; hh[0] = (_Float16)hs[2 * tid]; hh[1] = (_Float16)hs[2 * tid + 1];
      ((unsigned int*)h2p)[tid] = __builtin_bit_cast(unsigned int, hh); }
    __syncthreads();
    const float* g = G + ((size_t)(b * 32 + t)) * 1024 + dir * 512;
    float a0 = g[tid], a1 = g[tid + 256];
#pragma unroll 4
    for (int kq = 0; kq < 128; ++kq) {
      uint4 wv = W[kq * 256 + tid];
      uint2 hp = h2p[kq];
      h2v p = as_h2(hp.x), q = as_h2(hp.y);
      a0 = FDOT2(as_h2(wv.x), p, a0);
      a1 = FDOT2(as_h2(wv.y), p, a1);
      a0 = FDOT2(as_h2(wv.z), q, a0);
      a1 = FDOT2(as_h2(wv.w), q, a1);
    }
    __syncthreads();
    float n0 = tanhf(a0), n1 = tanhf(a1);
    hs[tid] = n0; hs[tid + 256] = n1;
    float* Ht = H + ((size_t)((dir * 64 + b) * 32 + t)) * 512;
    Ht[tid] = n0; Ht[tid + 256] = n1;
    __syncthreads();
  }
}

// ---------------- K5: preds = [hf;hb] @ cls_w^T + cls_b -> out[64][32][5] ---------------------
__global__ void pred_kernel(const float* __restrict__ H, const float* __restrict__ cw,
                            const float* __restrict__ cb, float* __restrict__ out) {
  const int bt = blockIdx.x;            // b*32 + t
  const int lane = threadIdx.x;         // 64
  const int b = bt >> 5, t = bt & 31;
  const float* hf = H + ((size_t)(b * 32 + t)) * 512;
  const float* hb = H + ((size_t)((64 + b) * 32 + t)) * 512;
  for (int c = 0; c < 5; ++c) {
    const float* w = cw + c * 1024;
    float a = 0.f;
    for (int o = lane; o < 512; o += 64) a += w[o] * hf[o] + w[512 + o] * hb[o];
#pragma unroll
    for (int d = 32; d; d >>= 1) a += __shfl_down(a, d, 64);
    if (lane == 0) out[bt * 5 + c] = a + cb[c];
  }
}

// ------------------------------------------------------------------------------------------------
extern "C" void kernel_launch(void* const* d_in, const int* in_sizes, int n_in,
                              void* d_out, int out_size, void* d_ws, size_t ws_size,
                              hipStream_t stream) {
  const int*   tok  = (const int*)d_in[0];
  const float* emb  = (const float*)d_in[1];
  const float* w3   = (const float*)d_in[2];
  const float* b3   = (const float*)d_in[3];
  const float* w4   = (const float*)d_in[4];
  const float* b4   = (const float*)d_in[5];
  const float* w5   = (const float*)d_in[6];
  const float* b5   = (const float*)d_in[7];
  const float* pw   = (const float*)d_in[8];
  const float* pb   = (const float*)d_in[9];
  const float* iw   = (const float*)d_in[10];
  const float* ib   = (const float*)d_in[11];
  const float* wihf = (const float*)d_in[12];
  const float* whhf = (const float*)d_in[13];
  const float* bihf = (const float*)d_in[14];
  const float* bhhf = (const float*)d_in[15];
  const float* wihb = (const float*)d_in[16];
  const float* whhb = (const float*)d_in[17];
  const float* bihb = (const float*)d_in[18];
  const float* bhhb = (const float*)d_in[19];
  const float* cw   = (const float*)d_in[20];
  const float* cb   = (const float*)d_in[21];
  float* out = (float*)d_out;

  char* ws = (char*)d_ws;
  __bf16* Aw   = (__bf16*)(ws);                         //  0MB: 860 KB
  uint4* Wq    = (uint4*)(ws +  1u * 1024 * 1024);      //  1MB: 1 MB
  float* sent  = (float*)(ws +  2u * 1024 * 1024);      //  2MB: 2.4 MB
  float* G     = (float*)(ws +  8u * 1024 * 1024);      //  8MB: 8 MB
  float* h0    = (float*)(ws + 16u * 1024 * 1024);      // 16MB: 128 KB
  float* H     = (float*)(ws + 17u * 1024 * 1024);      // 17MB: 16 MB (end 33MB)

  prep_convw<<<1680, 256, 0, stream>>>(w3, w4, w5, Aw);
  prep_whh<<<256, 256, 0, stream>>>(whhf, whhb, Wq);

  hipFuncSetAttribute(reinterpret_cast<const void*>(conv_kernel),
                      hipFuncAttributeMaxDynamicSharedMemorySize, LDSBYTES);
  conv_kernel<<<2048, 256, LDSBYTES, stream>>>(tok, emb, Aw, b3, b4, b5, sent);

  xig_kernel<<<256, 256, 0, stream>>>(sent, pw, pb, wihf, wihb, bihf, bhhf, bihb, bhhb, G);
  h0_kernel<<<8, 256, 0, stream>>>(sent, iw, ib, h0);
  rnn_kernel<<<128, 256, 0, stream>>>(Wq, G, h0, H);
  pred_kernel<<<2048, 64, 0, stream>>>(H, cw, cb, out);
}